// Round 1
// baseline (30538.370 us; speedup 1.0000x reference)
//
#include <hip/hip_runtime.h>
#include <cstdint>
#include <cstddef>

// R1: persistent slice-exchange RNN.
// 256 WGs = 4 slice-WGs per batch element x 64 batches, 512 threads each.
// Each WG holds a 128-row slice of W_hh in VGPRs (fp32), computes its slice of
// h_t each step, exchanges slices with its 3 siblings via a depth-2 global
// ring + per-batch monotonic counter (agent-scope atomics).
// Out-projection (O=64 -> 16 outputs per WG) is computed from the staged full
// h vector AFTER the signal, off the inter-WG critical path.

#define BB 64
#define TT 1024
#define II 64
#define HH 512
#define OO 64

__device__ __forceinline__ float tanh_fast(float v) {
  // tanh(|v|) = 1 - 2/(exp2(2*log2(e)*|v|) + 1), exact sign via copysign
  float e = exp2f(fabsf(v) * 2.8853900817779268f);
  float r = 1.0f - 2.0f * __builtin_amdgcn_rcpf(e + 1.0f);
  return copysignf(r, v);
}

__global__ __launch_bounds__(512, 2) void rnn_persist(
    const float* __restrict__ x, const float* __restrict__ h0,
    const float* __restrict__ Wih, const float* __restrict__ Whh,
    const float* __restrict__ bih, const float* __restrict__ bhh,
    const float* __restrict__ Wout, const float* __restrict__ bout,
    float* __restrict__ out, unsigned* __restrict__ cnt,
    float* __restrict__ ring) {
  const int tid = threadIdx.x;
  const int b   = blockIdx.x >> 2;   // batch element
  const int q   = blockIdx.x & 3;    // slice quarter
  const int n   = tid >> 2;          // local output row 0..127
  const int q4  = tid & 3;           // k-quarter (128 k's each)
  const int row = q * 128 + n;       // global row in H

  // staged h_{t-1}: split into 4 padded quarters to avoid LDS bank conflicts
  __shared__ float h2[2][4][132];
  __shared__ float x2[2][II];

  // ---- register-resident weights ----
  float wh[128];
#pragma unroll
  for (int j = 0; j < 32; ++j) {
    const float4 v = *(const float4*)(Whh + (size_t)row * HH + q4 * 128 + j * 4);
    wh[4*j+0] = v.x; wh[4*j+1] = v.y; wh[4*j+2] = v.z; wh[4*j+3] = v.w;
  }
  float wi[16];
#pragma unroll
  for (int j = 0; j < 4; ++j) {
    const float4 v = *(const float4*)(Wih + (size_t)row * II + q4 * 16 + j * 4);
    wi[4*j+0] = v.x; wi[4*j+1] = v.y; wi[4*j+2] = v.z; wi[4*j+3] = v.w;
  }
  const float bias_n = bih[row] + bhh[row];

  // out-proj: waves 0-3 only. 16 outputs, 16 lanes per output (k-chunks of 32).
  const int l     = tid & 63;
  const int oc    = l & 15;
  const int o_loc = (tid >> 6) * 4 + (l >> 4);
  float wo[32];
  float bo = 0.0f;
  if (tid < 256) {
    const int o = q * 16 + o_loc;
#pragma unroll
    for (int j = 0; j < 8; ++j) {
      const float4 v = *(const float4*)(Wout + (size_t)o * HH + oc * 32 + j * 4);
      wo[4*j+0] = v.x; wo[4*j+1] = v.y; wo[4*j+2] = v.z; wo[4*j+3] = v.w;
    }
    bo = bout[o];
  } else {
#pragma unroll
    for (int j = 0; j < 32; ++j) wo[j] = 0.0f;
  }

  const float* xb   = x + (size_t)b * TT * II;
  float* ringb      = ring + (size_t)b * 2 * HH;
  unsigned* cb      = cnt + b;
  float* outb       = out + (size_t)b * TT * OO;

  float2 hl = make_float2(0.0f, 0.0f);

  for (int t = 1; t <= TT + 1; ++t) {
    const int hs = (t - 1) & 1;  // ring/LDS slot holding h_{t-1}

    // stage x[b, t-1] -> x2[t&1] (independent of sync; overlaps the spin)
    if (t <= TT && tid >= 256 && tid < 272) {
      const int j = tid - 256;
      const float4 v = *(const float4*)(xb + (size_t)(t - 1) * II + j * 4);
      *(float4*)&x2[t & 1][j * 4] = v;
    }

    // obtain full h_{t-1} and stage into LDS (waves 0-3 only; others park at barrier)
    if (tid < 256) {
      if (t == 1) {
        hl = *(const float2*)(h0 + (size_t)b * HH + tid * 2);
      } else {
        const unsigned target = 4u * (unsigned)(t - 1);
        while (__hip_atomic_load(cb, __ATOMIC_RELAXED, __HIP_MEMORY_SCOPE_AGENT) < target) {
          __builtin_amdgcn_s_sleep(1);
        }
        __threadfence();  // acquire: invalidate caches before reading slices
        hl = *(const float2*)(ringb + (size_t)hs * HH + tid * 2);
      }
      const int el = tid * 2;
      h2[hs][el >> 7][el & 127]       = hl.x;
      h2[hs][el >> 7][(el & 127) + 1] = hl.y;
    }
    __syncthreads();

    if (t <= TT) {
      // ---- recurrent matvec: this thread's 128-k chunk of row `row` ----
      const float* hp = &h2[hs][q4][0];
      float a0 = 0.f, a1 = 0.f, a2 = 0.f, a3 = 0.f;
#pragma unroll
      for (int j = 0; j < 128; j += 4) {
        a0 = fmaf(wh[j+0], hp[j+0], a0);
        a1 = fmaf(wh[j+1], hp[j+1], a1);
        a2 = fmaf(wh[j+2], hp[j+2], a2);
        a3 = fmaf(wh[j+3], hp[j+3], a3);
      }
      // ---- input projection (I=64, 16 i's per thread) ----
      float ax = 0.f;
      const float* xp = &x2[t & 1][q4 * 16];
#pragma unroll
      for (int j = 0; j < 16; ++j) ax = fmaf(wi[j], xp[j], ax);

      float a = (a0 + a1) + (a2 + a3) + ax;
      a += __shfl_xor(a, 1);
      a += __shfl_xor(a, 2);
      if (q4 == 0) {
        const float hnew = tanh_fast(a + bias_n);
        __hip_atomic_store(&ringb[(size_t)(t & 1) * HH + row], hnew,
                           __ATOMIC_RELAXED, __HIP_MEMORY_SCOPE_AGENT);
      }
      __syncthreads();  // drains vmcnt: all slice stores complete before signal
      if (tid == 0) {
        __hip_atomic_fetch_add(cb, 1u, __ATOMIC_RELEASE, __HIP_MEMORY_SCOPE_AGENT);
      }
    }

    // ---- out-projection for tau = t-2 (uses h_{t-1} staged this step) ----
    // placed after the signal: off the inter-WG critical path
    if (t >= 2 && tid < 256) {
      const int kq = oc >> 2;
      const int kb = (oc & 3) * 32;
      const float* hq = &h2[hs][kq][kb];
      float s0 = 0.f, s1 = 0.f;
#pragma unroll
      for (int j = 0; j < 32; j += 2) {
        s0 = fmaf(wo[j+0], hq[j+0], s0);
        s1 = fmaf(wo[j+1], hq[j+1], s1);
      }
      float s = s0 + s1;
      s += __shfl_xor(s, 1);
      s += __shfl_xor(s, 2);
      s += __shfl_xor(s, 4);
      s += __shfl_xor(s, 8);
      if (oc == 0) {
        outb[(size_t)(t - 2) * OO + q * 16 + o_loc] = tanh_fast(s + bo);
      }
    }

    // ---- final hidden state h_T -> d_out tail ----
    if (t == TT + 1 && q == 0 && tid < 256) {
      float* hout = out + (size_t)BB * TT * OO + (size_t)b * HH + tid * 2;
      hout[0] = hl.x;
      hout[1] = hl.y;
    }
  }
}

extern "C" void kernel_launch(void* const* d_in, const int* in_sizes, int n_in,
                              void* d_out, int out_size, void* d_ws, size_t ws_size,
                              hipStream_t stream) {
  (void)in_sizes; (void)n_in; (void)out_size; (void)ws_size;
  const float* x    = (const float*)d_in[0];
  const float* h0   = (const float*)d_in[1];
  const float* Wih  = (const float*)d_in[2];
  const float* Whh  = (const float*)d_in[3];
  const float* bih  = (const float*)d_in[4];
  const float* bhh  = (const float*)d_in[5];
  const float* Wout = (const float*)d_in[6];
  const float* bout = (const float*)d_in[7];
  float* out = (float*)d_out;

  unsigned char* ws = (unsigned char*)d_ws;
  unsigned* cnt = (unsigned*)ws;             // 64 u32 counters (first 1KB)
  float* ring   = (float*)(ws + 1024);       // 64 x 2 x 512 f32 = 256 KB

  // counters must be zero at the start of every (replayed) launch
  hipMemsetAsync(d_ws, 0, 1024, stream);

  rnn_persist<<<dim3(256), dim3(512), 0, stream>>>(
      x, h0, Wih, Whh, bih, bhh, Wout, bout, out, cnt, ring);
}

// Round 2
// 9489.298 us; speedup vs baseline: 3.2182x; 3.2182x over previous
//
#include <hip/hip_runtime.h>
#include <cstdint>
#include <cstddef>

// R2: persistent slice-exchange RNN, spill-free + fence-free.
// 256 WGs = 4 slice-WGs per batch x 64 batches, 512 threads each.
// blockIdx remap: b = bid & 63, q = bid >> 6  -> all 4 siblings of a batch
// land on the same XCD under round-robin dispatch (perf heuristic only).
// Each WG holds a 128-row slice of W_hh in VGPRs (fp32, ~128 regs).
// Inter-WG exchange: depth-2 global ring written/read with RELAXED agent-scope
// atomics (coherence-point ops, no cache invalidation) + per-batch monotonic
// flag counter. Ordering: explicit s_waitcnt vmcnt(0) + __syncthreads before
// the flag increment.

#define BB 64
#define TT 1024
#define II 64
#define HH 512
#define OO 64

__device__ __forceinline__ float tanh_fast(float v) {
  float e = exp2f(fabsf(v) * 2.8853900817779268f);
  float r = 1.0f - 2.0f * __builtin_amdgcn_rcpf(e + 1.0f);
  return copysignf(r, v);
}

__global__ __launch_bounds__(512, 1) void rnn_persist(
    const float* __restrict__ x, const float* __restrict__ h0,
    const float* __restrict__ Wih, const float* __restrict__ Whh,
    const float* __restrict__ bih, const float* __restrict__ bhh,
    const float* __restrict__ Wout, const float* __restrict__ bout,
    float* __restrict__ out, unsigned* __restrict__ cnt,
    float* __restrict__ ring) {
  const int tid = threadIdx.x;
  const int b   = blockIdx.x & 63;   // batch element (siblings share XCD)
  const int q   = blockIdx.x >> 6;   // slice quarter
  const int n   = tid >> 2;          // local output row 0..127
  const int q4  = tid & 3;           // k-quarter (128 k's each)
  const int row = q * 128 + n;       // global row in H

  __shared__ float h2[2][4][132];
  __shared__ float x2[2][II];

  // ---- register-resident weights ----
  float wh[128];
#pragma unroll
  for (int j = 0; j < 32; ++j) {
    const float4 v = *(const float4*)(Whh + (size_t)row * HH + q4 * 128 + j * 4);
    wh[4*j+0] = v.x; wh[4*j+1] = v.y; wh[4*j+2] = v.z; wh[4*j+3] = v.w;
  }
  float wi[16];
#pragma unroll
  for (int j = 0; j < 4; ++j) {
    const float4 v = *(const float4*)(Wih + (size_t)row * II + q4 * 16 + j * 4);
    wi[4*j+0] = v.x; wi[4*j+1] = v.y; wi[4*j+2] = v.z; wi[4*j+3] = v.w;
  }
  const float bias_n = bih[row] + bhh[row];

  // out-proj: waves 0-3 only. 16 outputs/WG, 16 lanes per output.
  const int l     = tid & 63;
  const int oc    = l & 15;
  const int o_loc = (tid >> 6) * 4 + (l >> 4);
  float wo[32];
  float bo = 0.0f;
  if (tid < 256) {
    const int o = q * 16 + o_loc;
#pragma unroll
    for (int j = 0; j < 8; ++j) {
      const float4 v = *(const float4*)(Wout + (size_t)o * HH + oc * 32 + j * 4);
      wo[4*j+0] = v.x; wo[4*j+1] = v.y; wo[4*j+2] = v.z; wo[4*j+3] = v.w;
    }
    bo = bout[o];
  }

  const float* xb   = x + (size_t)b * TT * II;
  float* ringb      = ring + (size_t)b * 2 * HH;
  unsigned* cb      = cnt + b;
  float* outb       = out + (size_t)b * TT * OO;

  float2 hl = make_float2(0.0f, 0.0f);

  for (int t = 1; t <= TT + 1; ++t) {
    const int hs = (t - 1) & 1;  // ring/LDS slot holding h_{t-1}

    // stage x[b, t-1] -> x2[t&1] (overlaps the spin)
    if (t <= TT && tid >= 256 && tid < 272) {
      const int j = tid - 256;
      const float4 v = *(const float4*)(xb + (size_t)(t - 1) * II + j * 4);
      *(float4*)&x2[t & 1][j * 4] = v;
    }

    // obtain full h_{t-1} and stage into LDS (waves 0-3 only)
    if (tid < 256) {
      if (t == 1) {
        hl = *(const float2*)(h0 + (size_t)b * HH + tid * 2);
      } else {
        const unsigned target = 4u * (unsigned)(t - 1);
        while (__hip_atomic_load(cb, __ATOMIC_RELAXED, __HIP_MEMORY_SCOPE_AGENT) < target) {
          __builtin_amdgcn_s_sleep(1);
        }
        // ring data written/read as agent-scope atomics -> coherence point,
        // no stale L1/L2 lines possible; no cache-invalidate fence needed.
        union { unsigned long long u; float2 f; } cvt;
        cvt.u = __hip_atomic_load(
            (const unsigned long long*)(ringb + (size_t)hs * HH + tid * 2),
            __ATOMIC_RELAXED, __HIP_MEMORY_SCOPE_AGENT);
        hl = cvt.f;
      }
      const int el = tid * 2;
      h2[hs][el >> 7][el & 127]       = hl.x;
      h2[hs][el >> 7][(el & 127) + 1] = hl.y;
    }
    __syncthreads();

    if (t <= TT) {
      // ---- recurrent matvec: this thread's 128-k chunk of row `row` ----
      const float* hp = &h2[hs][q4][0];
      float a0 = 0.f, a1 = 0.f, a2 = 0.f, a3 = 0.f;
#pragma unroll
      for (int j = 0; j < 128; j += 4) {
        a0 = fmaf(wh[j+0], hp[j+0], a0);
        a1 = fmaf(wh[j+1], hp[j+1], a1);
        a2 = fmaf(wh[j+2], hp[j+2], a2);
        a3 = fmaf(wh[j+3], hp[j+3], a3);
      }
      // ---- input projection ----
      float ax = 0.f;
      const float* xp = &x2[t & 1][q4 * 16];
#pragma unroll
      for (int j = 0; j < 16; ++j) ax = fmaf(wi[j], xp[j], ax);

      float a = (a0 + a1) + (a2 + a3) + ax;
      a += __shfl_xor(a, 1);
      a += __shfl_xor(a, 2);
      if (q4 == 0) {
        const float hnew = tanh_fast(a + bias_n);
        __hip_atomic_store(&ringb[(size_t)(t & 1) * HH + row], hnew,
                           __ATOMIC_RELAXED, __HIP_MEMORY_SCOPE_AGENT);
      }
      // drain this wave's outstanding stores, then barrier: after the barrier
      // every slice store of this WG is at the coherence point.
      asm volatile("s_waitcnt vmcnt(0)" ::: "memory");
      __syncthreads();
      if (tid == 0) {
        __hip_atomic_fetch_add(cb, 1u, __ATOMIC_RELAXED, __HIP_MEMORY_SCOPE_AGENT);
      }
    }

    // ---- out-projection for tau = t-2 (off the inter-WG critical path) ----
    if (t >= 2 && tid < 256) {
      const int kq = oc >> 2;
      const int kb = (oc & 3) * 32;
      const float* hq = &h2[hs][kq][kb];
      float s0 = 0.f, s1 = 0.f;
#pragma unroll
      for (int j = 0; j < 32; j += 2) {
        s0 = fmaf(wo[j+0], hq[j+0], s0);
        s1 = fmaf(wo[j+1], hq[j+1], s1);
      }
      float s = s0 + s1;
      s += __shfl_xor(s, 1);
      s += __shfl_xor(s, 2);
      s += __shfl_xor(s, 4);
      s += __shfl_xor(s, 8);
      if (oc == 0) {
        outb[(size_t)(t - 2) * OO + q * 16 + o_loc] = tanh_fast(s + bo);
      }
    }

    // ---- final hidden state h_T -> d_out tail ----
    if (t == TT + 1 && q == 0 && tid < 256) {
      float* hout = out + (size_t)BB * TT * OO + (size_t)b * HH + tid * 2;
      hout[0] = hl.x;
      hout[1] = hl.y;
    }
  }
}

extern "C" void kernel_launch(void* const* d_in, const int* in_sizes, int n_in,
                              void* d_out, int out_size, void* d_ws, size_t ws_size,
                              hipStream_t stream) {
  (void)in_sizes; (void)n_in; (void)out_size; (void)ws_size;
  const float* x    = (const float*)d_in[0];
  const float* h0   = (const float*)d_in[1];
  const float* Wih  = (const float*)d_in[2];
  const float* Whh  = (const float*)d_in[3];
  const float* bih  = (const float*)d_in[4];
  const float* bhh  = (const float*)d_in[5];
  const float* Wout = (const float*)d_in[6];
  const float* bout = (const float*)d_in[7];
  float* out = (float*)d_out;

  unsigned char* ws = (unsigned char*)d_ws;
  unsigned* cnt = (unsigned*)ws;             // 64 u32 counters (first 1KB)
  float* ring   = (float*)(ws + 1024);       // 64 x 2 x 512 f32 = 256 KB

  hipMemsetAsync(d_ws, 0, 1024, stream);

  rnn_persist<<<dim3(256), dim3(512), 0, stream>>>(
      x, h0, Wih, Whh, bih, bhh, Wout, bout, out, cnt, ring);
}

// Round 3
// 4890.309 us; speedup vs baseline: 6.2447x; 1.9404x over previous
//
#include <hip/hip_runtime.h>
#include <cstdint>
#include <cstddef>

// R3: persistent slice-exchange RNN — contention-free sync.
// 256 WGs = 4 slice-WGs per batch x 64 batches, 512 threads each.
// b = bid & 63, q = bid >> 6 -> 4 siblings of a batch share an XCD under
// round-robin dispatch (perf heuristic only; correctness is agent-scope).
// Sync: single-writer per-(batch,quarter) flag words flag[b][q] = t (relaxed
// agent atomic store, NO RMW), padded to a 256B line per batch. Each stage
// wave polls only the flag of the quarter it stages (uniform same-address
// load), then reads that quarter from the depth-2 ring.
// Ordering: writer drains slice stores (s_waitcnt vmcnt(0) + barrier) before
// the flag store; reader has a false data-dependency from flag value into the
// ring address.

#define BB 64
#define TT 1024
#define II 64
#define HH 512
#define OO 64

__device__ __forceinline__ float tanh_fast(float v) {
  float e = exp2f(fabsf(v) * 2.8853900817779268f);
  float r = 1.0f - 2.0f * __builtin_amdgcn_rcpf(e + 1.0f);
  return copysignf(r, v);
}

__global__ __launch_bounds__(512, 1) void rnn_persist(
    const float* __restrict__ x, const float* __restrict__ h0,
    const float* __restrict__ Wih, const float* __restrict__ Whh,
    const float* __restrict__ bih, const float* __restrict__ bhh,
    const float* __restrict__ Wout, const float* __restrict__ bout,
    float* __restrict__ out, unsigned* __restrict__ flags,
    float* __restrict__ ring) {
  const int tid = threadIdx.x;
  const int b   = blockIdx.x & 63;   // batch element (siblings share XCD)
  const int q   = blockIdx.x >> 6;   // slice quarter
  const int n   = tid >> 2;          // local output row 0..127
  const int q4  = tid & 3;           // k-quarter (128 k's each)
  const int row = q * 128 + n;       // global row in H

  __shared__ float h2[2][4][132];
  __shared__ float x2[2][II];

  // ---- register-resident weights (VGPR+AGPR unified file) ----
  float wh[128];
#pragma unroll
  for (int j = 0; j < 32; ++j) {
    const float4 v = *(const float4*)(Whh + (size_t)row * HH + q4 * 128 + j * 4);
    wh[4*j+0] = v.x; wh[4*j+1] = v.y; wh[4*j+2] = v.z; wh[4*j+3] = v.w;
  }
  float wi[16];
#pragma unroll
  for (int j = 0; j < 4; ++j) {
    const float4 v = *(const float4*)(Wih + (size_t)row * II + q4 * 16 + j * 4);
    wi[4*j+0] = v.x; wi[4*j+1] = v.y; wi[4*j+2] = v.z; wi[4*j+3] = v.w;
  }
  const float bias_n = bih[row] + bhh[row];

  // out-proj: waves 0-3 only. 16 outputs/WG, 16 lanes per output.
  const int l     = tid & 63;
  const int oc    = l & 15;
  const int o_loc = (tid >> 6) * 4 + (l >> 4);
  float wo[32];
  float bo = 0.0f;
  if (tid < 256) {
    const int o = q * 16 + o_loc;
#pragma unroll
    for (int j = 0; j < 8; ++j) {
      const float4 v = *(const float4*)(Wout + (size_t)o * HH + oc * 32 + j * 4);
      wo[4*j+0] = v.x; wo[4*j+1] = v.y; wo[4*j+2] = v.z; wo[4*j+3] = v.w;
    }
    bo = bout[o];
  }

  const float* xb   = x + (size_t)b * TT * II;
  float* ringb      = ring + (size_t)b * 2 * HH;
  unsigned* flagb   = flags + (size_t)b * 64;  // 256B-padded flag line
  float* outb       = out + (size_t)b * TT * OO;

  float2 hl = make_float2(0.0f, 0.0f);

  for (int t = 1; t <= TT + 1; ++t) {
    const int hs = (t - 1) & 1;  // ring/LDS slot holding h_{t-1}

    // stage x[b, t-1] -> x2[t&1] (waves 4-7; overlaps the spin)
    if (t <= TT && tid >= 256 && tid < 272) {
      const int j = tid - 256;
      const float4 v = *(const float4*)(xb + (size_t)(t - 1) * II + j * 4);
      *(float4*)&x2[t & 1][j * 4] = v;
    }

    // obtain h_{t-1} and stage into LDS. Wave w stages quarter w and polls
    // only flag[w] -> quarters pipeline independently.
    if (tid < 256) {
      if (t == 1) {
        hl = *(const float2*)(h0 + (size_t)b * HH + tid * 2);
      } else {
        const int w = tid >> 6;  // quarter this thread stages
        const unsigned target = (unsigned)(t - 1);
        unsigned fv;
        while ((fv = __hip_atomic_load(flagb + w, __ATOMIC_RELAXED,
                                       __HIP_MEMORY_SCOPE_AGENT)) < target) {}
        int off = hs * HH + tid * 2;
        asm volatile("" : "+v"(off) : "v"(fv));  // false dep: no hoist
        union { unsigned long long u; float2 f; } cvt;
        cvt.u = __hip_atomic_load((const unsigned long long*)(ringb + off),
                                  __ATOMIC_RELAXED, __HIP_MEMORY_SCOPE_AGENT);
        hl = cvt.f;
      }
      const int el = tid * 2;
      h2[hs][el >> 7][el & 127]       = hl.x;
      h2[hs][el >> 7][(el & 127) + 1] = hl.y;
    }
    __syncthreads();

    if (t <= TT) {
      // ---- recurrent matvec: this thread's 128-k chunk of row `row` ----
      const float* hp = &h2[hs][q4][0];
      float a0 = 0.f, a1 = 0.f, a2 = 0.f, a3 = 0.f;
#pragma unroll
      for (int j = 0; j < 128; j += 4) {
        a0 = fmaf(wh[j+0], hp[j+0], a0);
        a1 = fmaf(wh[j+1], hp[j+1], a1);
        a2 = fmaf(wh[j+2], hp[j+2], a2);
        a3 = fmaf(wh[j+3], hp[j+3], a3);
      }
      // ---- input projection ----
      float ax = 0.f;
      const float* xp = &x2[t & 1][q4 * 16];
#pragma unroll
      for (int j = 0; j < 16; ++j) ax = fmaf(wi[j], xp[j], ax);

      float a = (a0 + a1) + (a2 + a3) + ax;
      a += __shfl_xor(a, 1);
      a += __shfl_xor(a, 2);
      if (q4 == 0) {
        const float hnew = tanh_fast(a + bias_n);
        __hip_atomic_store(&ringb[(size_t)(t & 1) * HH + row], hnew,
                           __ATOMIC_RELAXED, __HIP_MEMORY_SCOPE_AGENT);
      }
      // drain slice stores to the coherence point, then barrier: after this,
      // every slice store of this WG is globally visible.
      asm volatile("s_waitcnt vmcnt(0)" ::: "memory");
      __syncthreads();
      if (tid == 0) {
        __hip_atomic_store(flagb + q, (unsigned)t,
                           __ATOMIC_RELAXED, __HIP_MEMORY_SCOPE_AGENT);
      }
    }

    // ---- out-projection for tau = t-2 (off the inter-WG critical path) ----
    if (t >= 2 && tid < 256) {
      const int kq = oc >> 2;
      const int kb = (oc & 3) * 32;
      const float* hq = &h2[hs][kq][kb];
      float s0 = 0.f, s1 = 0.f;
#pragma unroll
      for (int j = 0; j < 32; j += 2) {
        s0 = fmaf(wo[j+0], hq[j+0], s0);
        s1 = fmaf(wo[j+1], hq[j+1], s1);
      }
      float s = s0 + s1;
      s += __shfl_xor(s, 1);
      s += __shfl_xor(s, 2);
      s += __shfl_xor(s, 4);
      s += __shfl_xor(s, 8);
      if (oc == 0) {
        outb[(size_t)(t - 2) * OO + q * 16 + o_loc] = tanh_fast(s + bo);
      }
    }

    // ---- final hidden state h_T -> d_out tail ----
    if (t == TT + 1 && q == 0 && tid < 256) {
      float* hout = out + (size_t)BB * TT * OO + (size_t)b * HH + tid * 2;
      hout[0] = hl.x;
      hout[1] = hl.y;
    }
  }
}

extern "C" void kernel_launch(void* const* d_in, const int* in_sizes, int n_in,
                              void* d_out, int out_size, void* d_ws, size_t ws_size,
                              hipStream_t stream) {
  (void)in_sizes; (void)n_in; (void)out_size; (void)ws_size;
  const float* x    = (const float*)d_in[0];
  const float* h0   = (const float*)d_in[1];
  const float* Wih  = (const float*)d_in[2];
  const float* Whh  = (const float*)d_in[3];
  const float* bih  = (const float*)d_in[4];
  const float* bhh  = (const float*)d_in[5];
  const float* Wout = (const float*)d_in[6];
  const float* bout = (const float*)d_in[7];
  float* out = (float*)d_out;

  unsigned char* ws = (unsigned char*)d_ws;
  unsigned* flags = (unsigned*)ws;             // 64 batches x 256B flag lines
  float* ring     = (float*)(ws + 64 * 256);   // 64 x 2 x 512 f32 = 256 KB

  // flags must be zero at the start of every (replayed) launch
  hipMemsetAsync(d_ws, 0, 64 * 256, stream);

  rnn_persist<<<dim3(256), dim3(512), 0, stream>>>(
      x, h0, Wih, Whh, bih, bhh, Wout, bout, out, flags, ring);
}

// Round 4
// 4040.544 us; speedup vs baseline: 7.5580x; 1.2103x over previous
//
#include <hip/hip_runtime.h>
#include <cstdint>
#include <cstddef>

// R4: persistent slice-exchange RNN — self-validating tagged ring.
// 256 WGs = 4 slice-WGs per batch x 64 batches, 512 threads each.
// b = bid & 63, q = bid >> 6 (siblings share an XCD under round-robin).
// Each h element is published as one 8B atomic word: (tag=t << 32) | fp32.
// Readers poll the data words directly until tag == t-1: the successful poll
// IS the data read. No flag, no vmcnt drain, ONE barrier per step.
// Writer also writes its own quarter straight into next step's LDS slot, so
// each WG polls only its 3 sibling quarters.
// Safety induction: WG q stores tag t only after its barrier, which follows
// observing tag t-1 on all rows, which implies every sibling's reads of slot
// t&1 (tag t-2) already returned data -> depth-2 ring never overruns.

#define BB 64
#define TT 1024
#define II 64
#define HH 512
#define OO 64

__device__ __forceinline__ float tanh_fast(float v) {
  float e = exp2f(fabsf(v) * 2.8853900817779268f);
  float r = 1.0f - 2.0f * __builtin_amdgcn_rcpf(e + 1.0f);
  return copysignf(r, v);
}

__global__ __launch_bounds__(512, 1) void rnn_persist(
    const float* __restrict__ x, const float* __restrict__ h0,
    const float* __restrict__ Wih, const float* __restrict__ Whh,
    const float* __restrict__ bih, const float* __restrict__ bhh,
    const float* __restrict__ Wout, const float* __restrict__ bout,
    float* __restrict__ out, unsigned long long* __restrict__ ring) {
  const int tid = threadIdx.x;
  const int b   = blockIdx.x & 63;   // batch element
  const int q   = blockIdx.x >> 6;   // slice quarter
  const int n   = tid >> 2;          // local output row 0..127
  const int q4  = tid & 3;           // k-quarter (128 k's each)
  const int row = q * 128 + n;       // global row in H

  __shared__ float h2[2][4][132];
  __shared__ float x2[2][II];

  // ---- register-resident weights ----
  float wh[128];
#pragma unroll
  for (int j = 0; j < 32; ++j) {
    const float4 v = *(const float4*)(Whh + (size_t)row * HH + q4 * 128 + j * 4);
    wh[4*j+0] = v.x; wh[4*j+1] = v.y; wh[4*j+2] = v.z; wh[4*j+3] = v.w;
  }
  float wi[16];
#pragma unroll
  for (int j = 0; j < 4; ++j) {
    const float4 v = *(const float4*)(Wih + (size_t)row * II + q4 * 16 + j * 4);
    wi[4*j+0] = v.x; wi[4*j+1] = v.y; wi[4*j+2] = v.z; wi[4*j+3] = v.w;
  }
  const float bias_n = bih[row] + bhh[row];

  // out-proj weights: waves 0-3 only. 16 outputs/WG, 16 lanes per output.
  const int l     = tid & 63;
  const int oc    = l & 15;
  const int o_loc = (tid >> 6) * 4 + (l >> 4);
  float wo[32];
  float bo = 0.0f;
  if (tid < 256) {
    const int o = q * 16 + o_loc;
#pragma unroll
    for (int j = 0; j < 8; ++j) {
      const float4 v = *(const float4*)(Wout + (size_t)o * HH + oc * 32 + j * 4);
      wo[4*j+0] = v.x; wo[4*j+1] = v.y; wo[4*j+2] = v.z; wo[4*j+3] = v.w;
    }
    bo = bout[o];
  }

  const float* xb              = x + (size_t)b * TT * II;
  unsigned long long* ringb    = ring + (size_t)b * 2 * HH;
  float* outb                  = out + (size_t)b * TT * OO;

  for (int t = 1; t <= TT + 1; ++t) {
    const int hs = (t - 1) & 1;  // LDS/ring slot holding h_{t-1}

    // stage x[b, t-1] -> x2[t&1] (wave 4 partial; overlaps sibling polls)
    if (t <= TT && tid >= 256 && tid < 272) {
      const int j = tid - 256;
      const float4 v = *(const float4*)(xb + (size_t)(t - 1) * II + j * 4);
      *(float4*)&x2[t & 1][j * 4] = v;
    }

    // stage h_{t-1}: wave w handles rows [64w*2 .. ), skips own quarter
    // (writer deposited it into h2[hs][q] last step).
    if (tid < 256) {
      const int w  = tid >> 6;
      const int e0 = tid * 2;
      if (t == 1) {
        const float2 hv = *(const float2*)(h0 + (size_t)b * HH + e0);
        h2[0][w][e0 & 127]       = hv.x;
        h2[0][w][(e0 & 127) + 1] = hv.y;
      } else if (w != q) {
        const unsigned tgt = (unsigned)(t - 1);
        const unsigned long long* p0 = ringb + (size_t)hs * HH + e0;
        unsigned long long v0 = __hip_atomic_load(p0,     __ATOMIC_RELAXED, __HIP_MEMORY_SCOPE_AGENT);
        unsigned long long v1 = __hip_atomic_load(p0 + 1, __ATOMIC_RELAXED, __HIP_MEMORY_SCOPE_AGENT);
        bool d0 = ((unsigned)(v0 >> 32) == tgt);
        bool d1 = ((unsigned)(v1 >> 32) == tgt);
        while (!(d0 && d1)) {
          if (!d0) v0 = __hip_atomic_load(p0,     __ATOMIC_RELAXED, __HIP_MEMORY_SCOPE_AGENT);
          if (!d1) v1 = __hip_atomic_load(p0 + 1, __ATOMIC_RELAXED, __HIP_MEMORY_SCOPE_AGENT);
          d0 = d0 | ((unsigned)(v0 >> 32) == tgt);
          d1 = d1 | ((unsigned)(v1 >> 32) == tgt);
        }
        union { unsigned u; float f; } c0, c1;
        c0.u = (unsigned)v0; c1.u = (unsigned)v1;
        h2[hs][w][e0 & 127]       = c0.f;
        h2[hs][w][(e0 & 127) + 1] = c1.f;
      }
    }
    __syncthreads();

    if (t <= TT) {
      // ---- recurrent matvec: this thread's 128-k chunk of row `row` ----
      const float* hp = &h2[hs][q4][0];
      float a0 = 0.f, a1 = 0.f, a2 = 0.f, a3 = 0.f;
#pragma unroll
      for (int j = 0; j < 128; j += 4) {
        a0 = fmaf(wh[j+0], hp[j+0], a0);
        a1 = fmaf(wh[j+1], hp[j+1], a1);
        a2 = fmaf(wh[j+2], hp[j+2], a2);
        a3 = fmaf(wh[j+3], hp[j+3], a3);
      }
      // ---- input projection ----
      float ax = 0.f;
      const float* xp = &x2[t & 1][q4 * 16];
#pragma unroll
      for (int j = 0; j < 16; ++j) ax = fmaf(wi[j], xp[j], ax);

      float a = (a0 + a1) + (a2 + a3) + ax;
      a += __shfl_xor(a, 1);
      a += __shfl_xor(a, 2);
      if (q4 == 0) {
        const float hnew = tanh_fast(a + bias_n);
        // own quarter directly into next step's LDS slot
        h2[t & 1][q][n] = hnew;
        // publish (tag | value) — self-validating, no drain, no flag
        union { float f; unsigned u; } cb; cb.f = hnew;
        __hip_atomic_store(ringb + (size_t)(t & 1) * HH + row,
                           ((unsigned long long)(unsigned)t << 32) | cb.u,
                           __ATOMIC_RELAXED, __HIP_MEMORY_SCOPE_AGENT);
      }
    }

    // ---- out-projection for tau = t-2 from h2[hs] (intact this interval) ----
    if (t >= 2 && tid < 256) {
      const int kq = oc >> 2;
      const int kb = (oc & 3) * 32;
      const float* hq = &h2[hs][kq][kb];
      float s0 = 0.f, s1 = 0.f;
#pragma unroll
      for (int j = 0; j < 32; j += 2) {
        s0 = fmaf(wo[j+0], hq[j+0], s0);
        s1 = fmaf(wo[j+1], hq[j+1], s1);
      }
      float s = s0 + s1;
      s += __shfl_xor(s, 1);
      s += __shfl_xor(s, 2);
      s += __shfl_xor(s, 4);
      s += __shfl_xor(s, 8);
      if (oc == 0) {
        outb[(size_t)(t - 2) * OO + q * 16 + o_loc] = tanh_fast(s + bo);
      }
    }

    // ---- final hidden state h_T -> d_out tail (from LDS, all rows present) ----
    if (t == TT + 1 && q == 0 && tid < 256) {
      const int e0 = tid * 2;
      float* hout = out + (size_t)BB * TT * OO + (size_t)b * HH + e0;
      hout[0] = h2[hs][e0 >> 7][e0 & 127];
      hout[1] = h2[hs][e0 >> 7][(e0 & 127) + 1];
    }
  }
}

extern "C" void kernel_launch(void* const* d_in, const int* in_sizes, int n_in,
                              void* d_out, int out_size, void* d_ws, size_t ws_size,
                              hipStream_t stream) {
  (void)in_sizes; (void)n_in; (void)out_size; (void)ws_size;
  const float* x    = (const float*)d_in[0];
  const float* h0   = (const float*)d_in[1];
  const float* Wih  = (const float*)d_in[2];
  const float* Whh  = (const float*)d_in[3];
  const float* bih  = (const float*)d_in[4];
  const float* bhh  = (const float*)d_in[5];
  const float* Wout = (const float*)d_in[6];
  const float* bout = (const float*)d_in[7];
  float* out = (float*)d_out;

  unsigned long long* ring = (unsigned long long*)d_ws;  // 64 x 2 x 512 x 8B = 512KB

  // tags must be 0 at the start of every (replayed) launch
  hipMemsetAsync(d_ws, 0, (size_t)BB * 2 * HH * 8, stream);

  rnn_persist<<<dim3(256), dim3(512), 0, stream>>>(
      x, h0, Wih, Whh, bih, bhh, Wout, bout, out, ring);
}